// Round 1
// baseline (141.597 us; speedup 1.0000x reference)
//
#include <hip/hip_runtime.h>
#include <math.h>

constexpr int H = 32, W = 32, C = 128, G = 4, K = 15, K2 = 225, GC = 32;
constexpr int NPIX = H * W;
constexpr int NOFF = G * K2 * 2;   // 1800
constexpr int NMSK = G * K2;       // 900
constexpr int KHID = 32;

// workspace layout (float offsets)
constexpr size_t WS_ENV    = 0;        // 225
constexpr size_t WS_KW     = 256;      // 28800 (flat (K2,C) MLP output)
constexpr size_t WS_SCALE  = 29184;    // 128
constexpr size_t WS_PART   = 29312;    // 4096
constexpr size_t WS_XPROJ  = 33792;    // 131072
constexpr size_t WS_XDW    = 164864;   // 131072
constexpr size_t WS_OUTPRE = 295936;   // 131072
constexpr size_t WS_OFFS   = 427008;   // 1843200
constexpr size_t WS_MASK   = 2270208;  // 921600  (ends 3191808 floats = 12.77 MB)

__device__ __forceinline__ float sigmoidf_(float v) { return 1.f / (1.f + expf(-v)); }
__device__ __forceinline__ float siluf_(float v)    { return v / (1.f + expf(-v)); }

// ---------------- Kernel A: sigma, env (normalized), kernel-MLP kw ----------------
__global__ void precompute_kernel(const float* __restrict__ raw_sigma,
                                  const float* __restrict__ k1_w, const float* __restrict__ k1_b,
                                  const float* __restrict__ k2_w, const float* __restrict__ k2_b,
                                  const float* __restrict__ k3_w, const float* __restrict__ k3_b,
                                  float* __restrict__ ws) {
    __shared__ float red[256];
    int tid = threadIdx.x;
    float xs = raw_sigma[0];
    // stable softplus (matches jax.nn.softplus = logaddexp(x,0))
    float sp = fmaxf(xs, 0.f) + log1pf(expf(-fabsf(xs)));
    float sigma = fminf(fmaxf(sp, 0.001f), 0.5f);
    float inv2s2 = 1.f / (2.f * sigma * sigma);

    int i = tid / 15, j = tid % 15;
    float gi = 0.f, gj = 0.f, e = 0.f;
    if (tid < K2) {
        gi = -0.5f + (float)i * (1.f / 14.f);
        gj = -0.5f + (float)j * (1.f / 14.f);
        e = expf(-(gi * gi + gj * gj) * inv2s2);
    }
    red[tid] = e;
    __syncthreads();
    for (int s = 128; s > 0; s >>= 1) {
        if (tid < s) red[tid] += red[tid + s];
        __syncthreads();
    }
    float esum = fmaxf(red[0], 1e-8f);
    if (tid < K2) {
        ws[WS_ENV + tid] = e / esum;

        // kernel MLP: pos = (gi*2, gj*2)
        float ph = gi * 2.f, pw = gj * 2.f;
        float h1[KHID], h2[KHID];
#pragma unroll
        for (int m = 0; m < KHID; m++) {
            float a = fmaf(ph, k1_w[m], fmaf(pw, k1_w[KHID + m], k1_b[m]));
            h1[m] = siluf_(a);
        }
#pragma unroll
        for (int m = 0; m < KHID; m++) {
            float a = k2_b[m];
#pragma unroll
            for (int q = 0; q < KHID; q++) a = fmaf(h1[q], k2_w[q * KHID + m], a);
            h2[m] = siluf_(a);
        }
        for (int m = 0; m < C; m++) {
            float a = k3_b[m];
#pragma unroll
            for (int q = 0; q < KHID; q++) a = fmaf(h2[q], k3_w[q * C + m], a);
            ws[WS_KW + (size_t)tid * C + m] = a;  // kw[g][k][c] = this_flat[g*7200 + k*32 + c]
        }
    }
}

// ---------------- Kernel B: x_proj, depthwise conv + silu, pointwise -> x_dw ----------------
__global__ void front_kernel(const float* __restrict__ x,
                             const float* __restrict__ w_in, const float* __restrict__ b_in,
                             const float* __restrict__ dw_k, const float* __restrict__ dw_b,
                             const float* __restrict__ pw_w, const float* __restrict__ pw_b,
                             float* __restrict__ ws) {
    int p = blockIdx.x;
    int h = p >> 5, w = p & 31;
    int c = threadIdx.x;
    __shared__ float xs[C], ts[C];
    xs[c] = x[(size_t)p * C + c];
    float y = dw_b[c];
#pragma unroll
    for (int dy = 0; dy < 3; dy++) {
        int hh = h + dy - 1;
        if (hh < 0 || hh >= H) continue;
#pragma unroll
        for (int dx = 0; dx < 3; dx++) {
            int wq = w + dx - 1;
            if (wq < 0 || wq >= W) continue;
            y = fmaf(x[((size_t)hh * W + wq) * C + c], dw_k[(dy * 3 + dx) * C + c], y);
        }
    }
    ts[c] = siluf_(y);
    __syncthreads();
    float accp = b_in[c], accd = pw_b[c];
    for (int i = 0; i < C; i++) {
        accp = fmaf(xs[i], w_in[i * C + c], accp);
        accd = fmaf(ts[i], pw_w[i * C + c], accd);
    }
    ws[WS_XPROJ + (size_t)p * C + c] = accp;
    ws[WS_XDW  + (size_t)p * C + c] = accd;
}

// ---------------- Kernel C: Y[p][n] = (x_dw[p]·W[:,n] + bias[n]) * scale(n) ----------------
// BM=16 pixels per block, 256 columns per block (one per thread).
__global__ __launch_bounds__(256) void gemm_kernel(const float* __restrict__ A,
                                                   const float* __restrict__ Wt,
                                                   const float* __restrict__ bias, int N,
                                                   const float* __restrict__ scale_scalar,
                                                   const float* __restrict__ env,
                                                   float* __restrict__ out) {
    __shared__ float a[16 * C];
    int tid = threadIdx.x;
    int p0 = blockIdx.y * 16;
    int n = blockIdx.x * 256 + tid;
#pragma unroll
    for (int e = 0; e < 8; e++) {
        int idx = e * 256 + tid;
        a[idx] = A[(size_t)p0 * C + idx];
    }
    __syncthreads();
    if (n < N) {
        float acc[16];
#pragma unroll
        for (int px = 0; px < 16; px++) acc[px] = 0.f;
        for (int i = 0; i < C; i++) {
            float wv = Wt[(size_t)i * N + n];
#pragma unroll
            for (int px = 0; px < 16; px++) acc[px] = fmaf(a[px * C + i], wv, acc[px]);
        }
        float b = bias[n];
        float sc = scale_scalar ? scale_scalar[0] : env[n % K2];
#pragma unroll
        for (int px = 0; px < 16; px++)
            out[(size_t)(p0 + px) * N + n] = (acc[px] + b) * sc;
    }
}

// ---------------- Kernel D: per-pixel softmax + bilinear deformable sampling ----------------
__global__ __launch_bounds__(256) void sampler_kernel(const float* __restrict__ ws_offs,
                                                      const float* __restrict__ ws_mask,
                                                      const float* __restrict__ xproj,
                                                      const float* __restrict__ kwf,
                                                      float* __restrict__ outpre) {
    int p = blockIdx.x;
    int h = p >> 5, w = p & 31;
    int tid = threadIdx.x;
    int lane = tid & 63;
    int wave = tid >> 6;  // == g for phase 1

    __shared__ float attn[NMSK];
    __shared__ float wgt[NMSK * 4];
    __shared__ int   loc[NMSK];
    __shared__ float psum[256];

    // phase 1: softmax over K2 per group (one wave per g)
    {
        const float* mrow = ws_mask + (size_t)p * NMSK + wave * K2;
        float v[4], ex[4];
        float mx = -1e30f;
#pragma unroll
        for (int q = 0; q < 4; q++) {
            int k = lane + q * 64;
            v[q] = (k < K2) ? mrow[k] : -1e30f;
            mx = fmaxf(mx, v[q]);
        }
#pragma unroll
        for (int s = 32; s > 0; s >>= 1) mx = fmaxf(mx, __shfl_xor(mx, s));
        float sum = 0.f;
#pragma unroll
        for (int q = 0; q < 4; q++) {
            int k = lane + q * 64;
            ex[q] = (k < K2) ? expf(v[q] - mx) : 0.f;
            sum += ex[q];
        }
#pragma unroll
        for (int s = 32; s > 0; s >>= 1) sum += __shfl_xor(sum, s);
        float inv = 1.f / sum;
#pragma unroll
        for (int q = 0; q < 4; q++) {
            int k = lane + q * 64;
            if (k < K2) attn[wave * K2 + k] = ex[q] * inv;
        }
    }
    __syncthreads();

    // phase 2: bilinear weights (attn * valid folded in) + integer locations
    for (int idx = tid; idx < NMSK; idx += 256) {
        int k = idx % K2;
        float oh = ws_offs[(size_t)p * NOFF + idx * 2 + 0];
        float ow = ws_offs[(size_t)p * NOFF + idx * 2 + 1];
        float abs_h = (float)(h + k / 15 - 7) + oh;
        float abs_w = (float)(w + k % 15 - 7) + ow;
        float validf = (abs_h < 0.f || abs_h > 31.f || abs_w < 0.f || abs_w > 31.f) ? 0.f : 1.f;
        float ah = fminf(fmaxf(abs_h, 0.f), 31.f);
        float aw = fminf(fmaxf(abs_w, 0.f), 31.f);
        int hf = (int)ah;
        int wf = (int)aw;
        float hwt = ah - (float)hf;
        float wwt = aw - (float)wf;
        float a = attn[idx] * validf;
        float u0 = 1.f - hwt, u1 = 1.f - wwt;
        wgt[idx * 4 + 0] = a * u0 * u1;
        wgt[idx * 4 + 1] = a * u0 * wwt;
        wgt[idx * 4 + 2] = a * hwt * u1;
        wgt[idx * 4 + 3] = a * hwt * wwt;
        loc[idx] = (hf << 8) | wf;
    }
    __syncthreads();

    // phase 3: out[g,c] = sum_k kw[g,k,c] * bilinear_sample   (k split over 2 half-waves)
    {
        int g = tid >> 6;
        int s = (tid >> 5) & 1;
        int c = tid & 31;
        int k0 = s ? 113 : 0;
        int k1 = s ? K2 : 113;
        const float* xp  = xproj + g * GC + c;
        const float* kwg = kwf + (size_t)g * (K2 * GC) + c;
        float acc = 0.f;
        for (int k = k0; k < k1; k++) {
            int idx = g * K2 + k;
            int l = loc[idx];
            int hf = l >> 8, wf = l & 255;
            int hc = min(hf + 1, 31), wc = min(wf + 1, 31);
            float x00 = xp[(hf * W + wf) * C];
            float x01 = xp[(hf * W + wc) * C];
            float x10 = xp[(hc * W + wf) * C];
            float x11 = xp[(hc * W + wc) * C];
            float samp = wgt[idx * 4 + 0] * x00 + wgt[idx * 4 + 1] * x01
                       + wgt[idx * 4 + 2] * x10 + wgt[idx * 4 + 3] * x11;
            acc = fmaf(kwg[(size_t)k * GC], samp, acc);
        }
        psum[tid] = acc;
    }
    __syncthreads();
    if (((tid >> 5) & 1) == 0) {
        int g = tid >> 6, c = tid & 31;
        outpre[(size_t)p * C + g * GC + c] = psum[tid] + psum[tid + 32];
    }
}

// ---------------- Kernel E1/E2: pooled mean + SE MLP ----------------
__global__ void reduce1_kernel(const float* __restrict__ outpre, float* __restrict__ part) {
    int b = blockIdx.x;
    int c = threadIdx.x;
    float s = 0.f;
    for (int q = 0; q < 32; q++) s += outpre[(size_t)(b * 32 + q) * C + c];
    part[(size_t)b * C + c] = s;
}

__global__ void se_kernel(const float* __restrict__ part,
                          const float* __restrict__ se1_w, const float* __restrict__ se1_b,
                          const float* __restrict__ se2_w, const float* __restrict__ se2_b,
                          float* __restrict__ scale_out) {
    __shared__ float pooled[C];
    __shared__ float hid[KHID];
    int tid = threadIdx.x;
    float s = 0.f;
    for (int b = 0; b < 32; b++) s += part[(size_t)b * C + tid];
    pooled[tid] = s * (1.f / 1024.f);
    __syncthreads();
    if (tid < KHID) {
        float a = se1_b[tid];
        for (int cc = 0; cc < C; cc++) a = fmaf(pooled[cc], se1_w[cc * KHID + tid], a);
        hid[tid] = siluf_(a);
    }
    __syncthreads();
    float a = se2_b[tid];
#pragma unroll
    for (int q = 0; q < KHID; q++) a = fmaf(hid[q], se2_w[q * C + tid], a);
    scale_out[tid] = sigmoidf_(a);
}

// ---------------- Kernel F: out = (out_pre * scale) @ w_out + b_out ----------------
__global__ void final_kernel(const float* __restrict__ outpre, const float* __restrict__ scale,
                             const float* __restrict__ w_out, const float* __restrict__ b_out,
                             float* __restrict__ out) {
    int p = blockIdx.x;
    int c = threadIdx.x;
    __shared__ float v[C];
    v[c] = outpre[(size_t)p * C + c] * scale[c];
    __syncthreads();
    float acc = b_out[c];
    for (int i = 0; i < C; i++) acc = fmaf(v[i], w_out[i * C + c], acc);
    out[(size_t)p * C + c] = acc;
}

extern "C" void kernel_launch(void* const* d_in, const int* in_sizes, int n_in,
                              void* d_out, int out_size, void* d_ws, size_t ws_size,
                              hipStream_t stream) {
    const float* x         = (const float*)d_in[0];
    const float* raw_sigma = (const float*)d_in[1];
    const float* bos       = (const float*)d_in[2];
    const float* w_in      = (const float*)d_in[3];
    const float* b_in      = (const float*)d_in[4];
    const float* w_out     = (const float*)d_in[5];
    const float* b_out     = (const float*)d_in[6];
    const float* dw_k      = (const float*)d_in[7];
    const float* dw_b      = (const float*)d_in[8];
    const float* pw_w      = (const float*)d_in[9];
    const float* pw_b      = (const float*)d_in[10];
    const float* off_w     = (const float*)d_in[11];
    const float* off_b     = (const float*)d_in[12];
    const float* msk_w     = (const float*)d_in[13];
    const float* msk_b     = (const float*)d_in[14];
    const float* k1_w      = (const float*)d_in[15];
    const float* k1_b      = (const float*)d_in[16];
    const float* k2_w      = (const float*)d_in[17];
    const float* k2_b      = (const float*)d_in[18];
    const float* k3_w      = (const float*)d_in[19];
    const float* k3_b      = (const float*)d_in[20];
    const float* se1_w     = (const float*)d_in[21];
    const float* se1_b     = (const float*)d_in[22];
    const float* se2_w     = (const float*)d_in[23];
    const float* se2_b     = (const float*)d_in[24];

    float* ws  = (float*)d_ws;
    float* out = (float*)d_out;

    precompute_kernel<<<1, 256, 0, stream>>>(raw_sigma, k1_w, k1_b, k2_w, k2_b, k3_w, k3_b, ws);
    front_kernel<<<NPIX, C, 0, stream>>>(x, w_in, b_in, dw_k, dw_b, pw_w, pw_b, ws);

    dim3 goff((NOFF + 255) / 256, NPIX / 16);
    gemm_kernel<<<goff, 256, 0, stream>>>(ws + WS_XDW, off_w, off_b, NOFF, bos, nullptr, ws + WS_OFFS);
    dim3 gmsk((NMSK + 255) / 256, NPIX / 16);
    gemm_kernel<<<gmsk, 256, 0, stream>>>(ws + WS_XDW, msk_w, msk_b, NMSK, nullptr, ws + WS_ENV, ws + WS_MASK);

    sampler_kernel<<<NPIX, 256, 0, stream>>>(ws + WS_OFFS, ws + WS_MASK, ws + WS_XPROJ, ws + WS_KW, ws + WS_OUTPRE);

    reduce1_kernel<<<32, C, 0, stream>>>(ws + WS_OUTPRE, ws + WS_PART);
    se_kernel<<<1, C, 0, stream>>>(ws + WS_PART, se1_w, se1_b, se2_w, se2_b, ws + WS_SCALE);
    final_kernel<<<NPIX, C, 0, stream>>>(ws + WS_OUTPRE, ws + WS_SCALE, w_out, b_out, out);
}

// Round 2
// 78.676 us; speedup vs baseline: 1.7997x; 1.7997x over previous
//
#include <hip/hip_runtime.h>
#include <math.h>

constexpr int H = 32, W = 32, C = 128, G = 4, K = 15, K2 = 225, GC = 32;
constexpr int NPIX = H * W;
constexpr int NOFF = G * K2 * 2;   // 1800
constexpr int NMSK = G * K2;       // 900
constexpr int NTOT = NOFF + NMSK;  // 2700
constexpr int KHID = 32;

// workspace layout (float offsets)
constexpr size_t WS_ENV    = 0;        // 225
constexpr size_t WS_KW     = 256;      // 28800 (flat (K2,C) MLP output)
constexpr size_t WS_SCALE  = 29184;    // 128
constexpr size_t WS_PART   = 29312;    // 4096
constexpr size_t WS_XPROJ  = 33792;    // 131072
constexpr size_t WS_XDW    = 164864;   // 131072
constexpr size_t WS_OUTPRE = 295936;   // 131072
constexpr size_t WS_OFFS   = 427008;   // 1843200
constexpr size_t WS_MASK   = 2270208;  // 921600

__device__ __forceinline__ float sigmoidf_(float v) { return 1.f / (1.f + expf(-v)); }
__device__ __forceinline__ float siluf_(float v)    { return v / (1.f + expf(-v)); }

// ---------------- env (sigma + normalized gaussian envelope) ----------------
__global__ void env_kernel(const float* __restrict__ raw_sigma, float* __restrict__ ws) {
    __shared__ float red[256];
    int tid = threadIdx.x;
    float xs = raw_sigma[0];
    float sp = fmaxf(xs, 0.f) + log1pf(expf(-fabsf(xs)));
    float sigma = fminf(fmaxf(sp, 0.001f), 0.5f);
    float inv2s2 = 1.f / (2.f * sigma * sigma);
    int i = tid / 15, j = tid % 15;
    float e = 0.f;
    if (tid < K2) {
        float gi = -0.5f + (float)i * (1.f / 14.f);
        float gj = -0.5f + (float)j * (1.f / 14.f);
        e = expf(-(gi * gi + gj * gj) * inv2s2);
    }
    red[tid] = e;
    __syncthreads();
    for (int s = 128; s > 0; s >>= 1) {
        if (tid < s) red[tid] += red[tid + s];
        __syncthreads();
    }
    float esum = fmaxf(red[0], 1e-8f);
    if (tid < K2) ws[WS_ENV + tid] = e / esum;
}

// ---------------- kernel-MLP kw: one block per grid point ----------------
__global__ void kwmlp_kernel(const float* __restrict__ k1_w, const float* __restrict__ k1_b,
                             const float* __restrict__ k2_w, const float* __restrict__ k2_b,
                             const float* __restrict__ k3_w, const float* __restrict__ k3_b,
                             float* __restrict__ ws) {
    int k2i = blockIdx.x;
    int t = threadIdx.x;
    int i = k2i / 15, j = k2i % 15;
    float ph = (-0.5f + (float)i * (1.f / 14.f)) * 2.f;
    float pw = (-0.5f + (float)j * (1.f / 14.f)) * 2.f;
    __shared__ float h1[KHID], h2[KHID];
    if (t < KHID) {
        float a = fmaf(ph, k1_w[t], fmaf(pw, k1_w[KHID + t], k1_b[t]));
        h1[t] = siluf_(a);
    }
    __syncthreads();
    if (t < KHID) {
        float a = k2_b[t];
#pragma unroll
        for (int q = 0; q < KHID; q++) a = fmaf(h1[q], k2_w[q * KHID + t], a);
        h2[t] = siluf_(a);
    }
    __syncthreads();
    float a = k3_b[t];
#pragma unroll
    for (int q = 0; q < KHID; q++) a = fmaf(h2[q], k3_w[q * C + t], a);
    ws[WS_KW + (size_t)k2i * C + t] = a;  // kw[g][k][c] = flat[g*7200 + k*32 + c]
}

// ---------------- front: x_proj, depthwise conv + silu, pointwise ----------------
__global__ void front_kernel(const float* __restrict__ x,
                             const float* __restrict__ w_in, const float* __restrict__ b_in,
                             const float* __restrict__ dw_k, const float* __restrict__ dw_b,
                             const float* __restrict__ pw_w, const float* __restrict__ pw_b,
                             float* __restrict__ ws) {
    int p = blockIdx.x;
    int h = p >> 5, w = p & 31;
    int c = threadIdx.x;
    __shared__ float xs[C], ts[C];
    xs[c] = x[(size_t)p * C + c];
    float y = dw_b[c];
#pragma unroll
    for (int dy = 0; dy < 3; dy++) {
        int hh = h + dy - 1;
        if (hh < 0 || hh >= H) continue;
#pragma unroll
        for (int dx = 0; dx < 3; dx++) {
            int wq = w + dx - 1;
            if (wq < 0 || wq >= W) continue;
            y = fmaf(x[((size_t)hh * W + wq) * C + c], dw_k[(dy * 3 + dx) * C + c], y);
        }
    }
    ts[c] = siluf_(y);
    __syncthreads();
    float accp = b_in[c], accd = pw_b[c];
    for (int i = 0; i < C; i += 4) {
        float4 xv = *(const float4*)&xs[i];
        float4 tv = *(const float4*)&ts[i];
        accp = fmaf(xv.x, w_in[(size_t)(i + 0) * C + c], accp);
        accp = fmaf(xv.y, w_in[(size_t)(i + 1) * C + c], accp);
        accp = fmaf(xv.z, w_in[(size_t)(i + 2) * C + c], accp);
        accp = fmaf(xv.w, w_in[(size_t)(i + 3) * C + c], accp);
        accd = fmaf(tv.x, pw_w[(size_t)(i + 0) * C + c], accd);
        accd = fmaf(tv.y, pw_w[(size_t)(i + 1) * C + c], accd);
        accd = fmaf(tv.z, pw_w[(size_t)(i + 2) * C + c], accd);
        accd = fmaf(tv.w, pw_w[(size_t)(i + 3) * C + c], accd);
    }
    ws[WS_XPROJ + (size_t)p * C + c] = accp;
    ws[WS_XDW  + (size_t)p * C + c] = accd;
}

// ---------------- combined offs+mask GEMM: tile 64(M) x 128(N), 4x8 per thread ----------------
__global__ __launch_bounds__(256) void offmsk_gemm(const float* __restrict__ A,
                                                   const float* __restrict__ off_w,
                                                   const float* __restrict__ off_b,
                                                   const float* __restrict__ msk_w,
                                                   const float* __restrict__ msk_b,
                                                   const float* __restrict__ bos,
                                                   const float* __restrict__ env,
                                                   float* __restrict__ offs_out,
                                                   float* __restrict__ mask_out) {
    __shared__ float At[32][72];   // transposed A tile: At[k][row], pad 8 -> conflict-free
    __shared__ float Bs[32][128];
    int tid = threadIdx.x;
    int c0 = blockIdx.x * 128;
    int p0 = blockIdx.y * 64;
    int tx = tid & 15, ty = tid >> 4;

    float acc[4][8];
#pragma unroll
    for (int i = 0; i < 4; i++)
#pragma unroll
        for (int j = 0; j < 8; j++) acc[i][j] = 0.f;

    // B-load setup: this thread loads float4 at column cB, rows kB + 8*pass
    int cB = c0 + (tid & 31) * 4;
    int kB = tid >> 5;
    bool bvalid = cB < NTOT;
    const float* bptr = nullptr;
    int bstride = 0;
    if (cB < NOFF)       { bptr = off_w + cB;          bstride = NOFF; }
    else if (bvalid)     { bptr = msk_w + (cB - NOFF); bstride = NMSK; }
    // A-load setup
    int rA = tid >> 3, k4A = (tid & 7) * 4;

    for (int kt = 0; kt < C; kt += 32) {
        if (kt) __syncthreads();
#pragma unroll
        for (int pass = 0; pass < 2; pass++) {
            int r = rA + pass * 32;
            float4 v = *(const float4*)&A[(size_t)(p0 + r) * C + kt + k4A];
            At[k4A + 0][r] = v.x; At[k4A + 1][r] = v.y;
            At[k4A + 2][r] = v.z; At[k4A + 3][r] = v.w;
        }
#pragma unroll
        for (int pass = 0; pass < 4; pass++) {
            int k = kB + pass * 8;
            float4 v = make_float4(0.f, 0.f, 0.f, 0.f);
            if (bvalid) v = *(const float4*)&bptr[(size_t)(kt + k) * bstride];
            *(float4*)&Bs[k][(tid & 31) * 4] = v;
        }
        __syncthreads();
#pragma unroll 8
        for (int k = 0; k < 32; k++) {
            const float4 a4 = *(const float4*)&At[k][ty * 4];
            const float4 b0 = *(const float4*)&Bs[k][tx * 8];
            const float4 b1 = *(const float4*)&Bs[k][tx * 8 + 4];
            const float av[4] = {a4.x, a4.y, a4.z, a4.w};
            const float bv[8] = {b0.x, b0.y, b0.z, b0.w, b1.x, b1.y, b1.z, b1.w};
#pragma unroll
            for (int i = 0; i < 4; i++)
#pragma unroll
                for (int j = 0; j < 8; j++)
                    acc[i][j] = fmaf(av[i], bv[j], acc[i][j]);
        }
    }

    // epilogue: 8 columns per thread, all in the same region (1800 % 8 == 0)
    int colbase = c0 + tx * 8;
    if (colbase >= NTOT) return;
    float bias[8], sc[8];
    float* obase;
    int ostride;
    bool full = (colbase + 8) <= NTOT;
    if (colbase < NOFF) {
        float s = bos[0];
#pragma unroll
        for (int j = 0; j < 8; j++) { bias[j] = off_b[colbase + j]; sc[j] = s; }
        obase = offs_out + colbase; ostride = NOFF;
    } else {
        int m0 = colbase - NOFF;
#pragma unroll
        for (int j = 0; j < 8; j++) {
            if (colbase + j < NTOT) { bias[j] = msk_b[m0 + j]; sc[j] = env[(m0 + j) % K2]; }
            else                    { bias[j] = 0.f; sc[j] = 0.f; }
        }
        obase = mask_out + m0; ostride = NMSK;
    }
#pragma unroll
    for (int i = 0; i < 4; i++) {
        size_t row = (size_t)(p0 + ty * 4 + i);
        if (full) {
            float4 r0 = make_float4((acc[i][0] + bias[0]) * sc[0], (acc[i][1] + bias[1]) * sc[1],
                                    (acc[i][2] + bias[2]) * sc[2], (acc[i][3] + bias[3]) * sc[3]);
            float4 r1 = make_float4((acc[i][4] + bias[4]) * sc[4], (acc[i][5] + bias[5]) * sc[5],
                                    (acc[i][6] + bias[6]) * sc[6], (acc[i][7] + bias[7]) * sc[7]);
            *(float4*)&obase[row * ostride]     = r0;
            *(float4*)&obase[row * ostride + 4] = r1;
        } else {
#pragma unroll
            for (int j = 0; j < 8; j++)
                if (colbase + j < NTOT)
                    obase[row * ostride + j] = (acc[i][j] + bias[j]) * sc[j];
        }
    }
}

// ---------------- sampler: softmax + bilinear deformable sampling ----------------
__global__ __launch_bounds__(256) void sampler_kernel(const float* __restrict__ ws_offs,
                                                      const float* __restrict__ ws_mask,
                                                      const float* __restrict__ xproj,
                                                      const float* __restrict__ kwf,
                                                      float* __restrict__ outpre) {
    int p = blockIdx.x;
    int h = p >> 5, w = p & 31;
    int tid = threadIdx.x;

    __shared__ float  attn[NMSK];
    __shared__ float4 wgt4[NMSK];
    __shared__ int4   loc4[NMSK];
    __shared__ float4 psum4[256];

    // phase 1: softmax over K2 per group (one wave per g)
    {
        int lane = tid & 63;
        int g = tid >> 6;
        const float* mrow = ws_mask + (size_t)p * NMSK + g * K2;
        float v[4], ex[4];
        float mx = -1e30f;
#pragma unroll
        for (int q = 0; q < 4; q++) {
            int k = lane + q * 64;
            v[q] = (k < K2) ? mrow[k] : -1e30f;
            mx = fmaxf(mx, v[q]);
        }
#pragma unroll
        for (int s = 32; s > 0; s >>= 1) mx = fmaxf(mx, __shfl_xor(mx, s));
        float sum = 0.f;
#pragma unroll
        for (int q = 0; q < 4; q++) {
            int k = lane + q * 64;
            ex[q] = (k < K2) ? expf(v[q] - mx) : 0.f;
            sum += ex[q];
        }
#pragma unroll
        for (int s = 32; s > 0; s >>= 1) sum += __shfl_xor(sum, s);
        float inv = 1.f / sum;
#pragma unroll
        for (int q = 0; q < 4; q++) {
            int k = lane + q * 64;
            if (k < K2) attn[g * K2 + k] = ex[q] * inv;
        }
    }
    __syncthreads();

    // phase 2: bilinear weights (attn*valid folded) + 4 precomputed element offsets
    for (int idx = tid; idx < NMSK; idx += 256) {
        int k = idx % K2;
        float2 o = *(const float2*)&ws_offs[(size_t)p * NOFF + idx * 2];
        float abs_h = (float)(h + k / 15 - 7) + o.x;
        float abs_w = (float)(w + k % 15 - 7) + o.y;
        float validf = (abs_h < 0.f || abs_h > 31.f || abs_w < 0.f || abs_w > 31.f) ? 0.f : 1.f;
        float ah = fminf(fmaxf(abs_h, 0.f), 31.f);
        float aw = fminf(fmaxf(abs_w, 0.f), 31.f);
        int hf = (int)ah, wf = (int)aw;
        int hc = min(hf + 1, 31), wc = min(wf + 1, 31);
        float hwt = ah - (float)hf, wwt = aw - (float)wf;
        float a = attn[idx] * validf;
        float u0 = 1.f - hwt, u1 = 1.f - wwt;
        wgt4[idx] = make_float4(a * u0 * u1, a * u0 * wwt, a * hwt * u1, a * hwt * wwt);
        loc4[idx] = make_int4((hf * W + wf) * C, (hf * W + wc) * C,
                              (hc * W + wf) * C, (hc * W + wc) * C);
    }
    __syncthreads();

    // phase 3: 4 g x 8 k-segments x 8 channel-quads; float4 everything
    {
        int g  = tid >> 6;
        int s  = (tid >> 3) & 7;
        int cq = (tid & 7) * 4;
        const float* xpg = xproj + g * GC + cq;
        const float* kwg = kwf + (size_t)g * (K2 * GC) + cq;
        float4 acc = make_float4(0.f, 0.f, 0.f, 0.f);
        int k0 = s * 28;
        int k1 = (s == 7) ? K2 : k0 + 28;
        for (int k = k0; k < k1; k++) {
            int idx = g * K2 + k;
            int4   A  = loc4[idx];
            float4 Wv = wgt4[idx];
            float4 x00 = *(const float4*)(xpg + A.x);
            float4 x01 = *(const float4*)(xpg + A.y);
            float4 x10 = *(const float4*)(xpg + A.z);
            float4 x11 = *(const float4*)(xpg + A.w);
            float4 kw4 = *(const float4*)(kwg + k * GC);
            float sx = fmaf(Wv.w, x11.x, fmaf(Wv.z, x10.x, fmaf(Wv.y, x01.x, Wv.x * x00.x)));
            float sy = fmaf(Wv.w, x11.y, fmaf(Wv.z, x10.y, fmaf(Wv.y, x01.y, Wv.x * x00.y)));
            float sz = fmaf(Wv.w, x11.z, fmaf(Wv.z, x10.z, fmaf(Wv.y, x01.z, Wv.x * x00.z)));
            float sw = fmaf(Wv.w, x11.w, fmaf(Wv.z, x10.w, fmaf(Wv.y, x01.w, Wv.x * x00.w)));
            acc.x = fmaf(kw4.x, sx, acc.x);
            acc.y = fmaf(kw4.y, sy, acc.y);
            acc.z = fmaf(kw4.z, sz, acc.z);
            acc.w = fmaf(kw4.w, sw, acc.w);
        }
        psum4[tid] = acc;
    }
    __syncthreads();
    if (((tid >> 3) & 7) == 0) {
        int g = tid >> 6, cq = (tid & 7) * 4;
        float4 r = psum4[tid];
#pragma unroll
        for (int ss = 1; ss < 8; ss++) {
            float4 q = psum4[tid + ss * 8];
            r.x += q.x; r.y += q.y; r.z += q.z; r.w += q.w;
        }
        *(float4*)&outpre[(size_t)p * C + g * GC + cq] = r;
    }
}

// ---------------- pooled mean + SE MLP ----------------
__global__ void reduce1_kernel(const float* __restrict__ outpre, float* __restrict__ part) {
    int b = blockIdx.x;
    int c = threadIdx.x;
    float s = 0.f;
    for (int q = 0; q < 32; q++) s += outpre[(size_t)(b * 32 + q) * C + c];
    part[(size_t)b * C + c] = s;
}

__global__ void se_kernel(const float* __restrict__ part,
                          const float* __restrict__ se1_w, const float* __restrict__ se1_b,
                          const float* __restrict__ se2_w, const float* __restrict__ se2_b,
                          float* __restrict__ scale_out) {
    __shared__ float pooled[C];
    __shared__ float hid[KHID];
    int tid = threadIdx.x;
    float s = 0.f;
    for (int b = 0; b < 32; b++) s += part[(size_t)b * C + tid];
    pooled[tid] = s * (1.f / 1024.f);
    __syncthreads();
    if (tid < KHID) {
        float a = se1_b[tid];
        for (int cc = 0; cc < C; cc++) a = fmaf(pooled[cc], se1_w[cc * KHID + tid], a);
        hid[tid] = siluf_(a);
    }
    __syncthreads();
    float a = se2_b[tid];
#pragma unroll
    for (int q = 0; q < KHID; q++) a = fmaf(hid[q], se2_w[q * C + tid], a);
    scale_out[tid] = sigmoidf_(a);
}

// ---------------- final: out = (out_pre * scale) @ w_out + b_out ----------------
__global__ void final_kernel(const float* __restrict__ outpre, const float* __restrict__ scale,
                             const float* __restrict__ w_out, const float* __restrict__ b_out,
                             float* __restrict__ out) {
    int p = blockIdx.x;
    int c = threadIdx.x;
    __shared__ float v[C];
    v[c] = outpre[(size_t)p * C + c] * scale[c];
    __syncthreads();
    float acc = b_out[c];
    for (int i = 0; i < C; i += 4) {
        float4 vv = *(const float4*)&v[i];
        acc = fmaf(vv.x, w_out[(size_t)(i + 0) * C + c], acc);
        acc = fmaf(vv.y, w_out[(size_t)(i + 1) * C + c], acc);
        acc = fmaf(vv.z, w_out[(size_t)(i + 2) * C + c], acc);
        acc = fmaf(vv.w, w_out[(size_t)(i + 3) * C + c], acc);
    }
    out[(size_t)p * C + c] = acc;
}

extern "C" void kernel_launch(void* const* d_in, const int* in_sizes, int n_in,
                              void* d_out, int out_size, void* d_ws, size_t ws_size,
                              hipStream_t stream) {
    const float* x         = (const float*)d_in[0];
    const float* raw_sigma = (const float*)d_in[1];
    const float* bos       = (const float*)d_in[2];
    const float* w_in      = (const float*)d_in[3];
    const float* b_in      = (const float*)d_in[4];
    const float* w_out     = (const float*)d_in[5];
    const float* b_out     = (const float*)d_in[6];
    const float* dw_k      = (const float*)d_in[7];
    const float* dw_b      = (const float*)d_in[8];
    const float* pw_w      = (const float*)d_in[9];
    const float* pw_b      = (const float*)d_in[10];
    const float* off_w     = (const float*)d_in[11];
    const float* off_b     = (const float*)d_in[12];
    const float* msk_w     = (const float*)d_in[13];
    const float* msk_b     = (const float*)d_in[14];
    const float* k1_w      = (const float*)d_in[15];
    const float* k1_b      = (const float*)d_in[16];
    const float* k2_w      = (const float*)d_in[17];
    const float* k2_b      = (const float*)d_in[18];
    const float* k3_w      = (const float*)d_in[19];
    const float* k3_b      = (const float*)d_in[20];
    const float* se1_w     = (const float*)d_in[21];
    const float* se1_b     = (const float*)d_in[22];
    const float* se2_w     = (const float*)d_in[23];
    const float* se2_b     = (const float*)d_in[24];

    float* ws  = (float*)d_ws;
    float* out = (float*)d_out;

    env_kernel<<<1, 256, 0, stream>>>(raw_sigma, ws);
    kwmlp_kernel<<<K2, C, 0, stream>>>(k1_w, k1_b, k2_w, k2_b, k3_w, k3_b, ws);
    front_kernel<<<NPIX, C, 0, stream>>>(x, w_in, b_in, dw_k, dw_b, pw_w, pw_b, ws);

    dim3 gg((NTOT + 127) / 128, NPIX / 64);
    offmsk_gemm<<<gg, 256, 0, stream>>>(ws + WS_XDW, off_w, off_b, msk_w, msk_b, bos,
                                        ws + WS_ENV, ws + WS_OFFS, ws + WS_MASK);

    sampler_kernel<<<NPIX, 256, 0, stream>>>(ws + WS_OFFS, ws + WS_MASK, ws + WS_XPROJ,
                                             ws + WS_KW, ws + WS_OUTPRE);

    reduce1_kernel<<<32, C, 0, stream>>>(ws + WS_OUTPRE, ws + WS_PART);
    se_kernel<<<1, C, 0, stream>>>(ws + WS_PART, se1_w, se1_b, se2_w, se2_b, ws + WS_SCALE);
    final_kernel<<<NPIX, C, 0, stream>>>(ws + WS_OUTPRE, ws + WS_SCALE, w_out, b_out, out);
}